// Round 1
// baseline (115.327 us; speedup 1.0000x reference)
//
#include <hip/hip_runtime.h>

// EfficientPairEmbed: out[0, e, h] = sum_g emb[anum[src_e], anum[dst_e], 0, h, g] * rbf[e, g]
// rbf[e,g] = exp(-0.5/std^2 * (dist_e - offset_g)^2), offsets = linspace(0, 12, 50), std = 12/50.
//
// R7: gather was L1-transaction-bound: 1 lane/edge issued 8 independent random 16B
// loads -> 64 distinct line lookups per wave instruction (~3 TB/s plateau).
// Now 8 lanes cooperate per edge (lane r loads window row r): each load instruction
// fetches 8 contiguous 128B windows (full coalescing, ~4x fewer transactions).
// Head sums reduced across the 8-lane group via 3-round ds_swizzle reduce-scatter,
// ending with lane r holding head r -> stores are 1 coalesced dword/lane.
// Output stores are nontemporal to keep the 8MB temb table resident in L2.

#define G_NUM 50
#define H_NUM 8
#define NE_NUM 100
#define N_PAIRS (NE_NUM * NE_NUM)
#define WIN 8
#define BLOCK_THREADS 256
#define WAVES_PB (BLOCK_THREADS / 64)
#define TP_PAIRS 8               // pairs per transpose block

#define SPACING (12.0f / (float)(G_NUM - 1))
#define INV_SPACING ((float)(G_NUM - 1) / 12.0f)
#define RBF_COEFF (-0.5f * ((float)G_NUM / 12.0f) * ((float)G_NUM / 12.0f))

__device__ __forceinline__ float bf_lo(unsigned u) { return __uint_as_float(u << 16); }
__device__ __forceinline__ float bf_hi(unsigned u) { return __uint_as_float(u & 0xffff0000u); }

// ds_swizzle xor-lane patterns (BitMode: (xor<<10) | 0x1F) — stay within 8-lane groups.
#define SWZ(x, pat) __int_as_float(__builtin_amdgcn_ds_swizzle(__float_as_int(x), (pat)))
#define SWZ_X1 0x041F
#define SWZ_X2 0x081F
#define SWZ_X4 0x101F

// ---------------- Pass 0: emb [p][h][g] fp32 -> temb [p][g][h] bf16, LDS-staged ----------------
__global__ __launch_bounds__(BLOCK_THREADS) void transpose_cast_kernel(
    const float* __restrict__ emb, unsigned int* __restrict__ temb)
{
    __shared__ float ls[TP_PAIRS * H_NUM * G_NUM];          // 3200 floats, 12.8 KB

    const int tid = threadIdx.x;
    const int p0  = blockIdx.x * TP_PAIRS;

    // Coalesced read: 800 float4 per block.
    const float4* src = (const float4*)(emb + (size_t)p0 * (H_NUM * G_NUM));
    #pragma unroll
    for (int i = tid; i < TP_PAIRS * H_NUM * G_NUM / 4; i += BLOCK_THREADS)
        ((float4*)ls)[i] = src[i];
    __syncthreads();

    // Coalesced write: 1600 packed-bf16 uints per block.
    unsigned int* dst = temb + (size_t)p0 * (H_NUM * G_NUM / 2);
    #pragma unroll
    for (int i = tid; i < TP_PAIRS * H_NUM * G_NUM / 2; i += BLOCK_THREADS) {
        int q  = i / (H_NUM * G_NUM / 2);          // local pair
        int u  = i - q * (H_NUM * G_NUM / 2);      // uint idx within pair: [g][h/2]
        int g  = u >> 2;
        int h0 = (u & 3) * 2;
        float f0 = ls[q * (H_NUM * G_NUM) + h0 * G_NUM + g];
        float f1 = ls[q * (H_NUM * G_NUM) + (h0 + 1) * G_NUM + g];
        unsigned u0 = __float_as_uint(f0);
        unsigned u1 = __float_as_uint(f1);
        unsigned b0 = (u0 + 0x7fffu + ((u0 >> 16) & 1u)) >> 16;   // RNE bf16
        unsigned b1 = (u1 + 0x7fffu + ((u1 >> 16) & 1u)) >> 16;
        dst[i] = (b1 << 16) | (b0 & 0xffffu);
    }
}

// ---------------- Pass 1: cooperative coalesced gather, 8 lanes/edge ----------------
__global__ __launch_bounds__(BLOCK_THREADS) void gather_kernel(
    const int* __restrict__ anum,
    const int* __restrict__ edge_index,
    const float* __restrict__ dist,
    const unsigned short* __restrict__ temb,
    float* __restrict__ out,
    int n_edges)
{
    // per-lane metadata staged through LDS (separate arrays: broadcast reads, no conflicts)
    __shared__ int   m_off[BLOCK_THREADS];   // short-offset of window row 0: p*400 + g0*8
    __shared__ float m_res[BLOCK_THREADS];   // dv - g0*SPACING

    const int tid  = threadIdx.x;
    const int lane = tid & 63;
    const int wv   = tid >> 6;
    const int row  = lane & 7;               // window row this lane loads
    const int grp  = lane >> 3;              // edge-within-batch

    const int we0 = (blockIdx.x * WAVES_PB + wv) * 64;   // first edge of this wave

    // ---- preload metadata: one edge per lane, fully coalesced streams ----
    {
        int e  = we0 + lane;
        int ec = e < n_edges ? e : (n_edges - 1);
        int s  = __builtin_nontemporal_load(edge_index + ec);
        int d  = __builtin_nontemporal_load(edge_index + n_edges + ec);
        float dv = __builtin_nontemporal_load(dist + ec);
        int p  = anum[s] * NE_NUM + anum[d];
        int g0 = (int)(dv * INV_SPACING) - 3;
        g0 = g0 < 0 ? 0 : g0;
        g0 = g0 > (G_NUM - WIN) ? (G_NUM - WIN) : g0;
        m_off[tid] = p * (G_NUM * H_NUM) + g0 * H_NUM;
        m_res[tid] = dv - (float)g0 * SPACING;
    }
    // same-wave LDS write->read: hardware-ordered, no barrier needed.

    // ---- phase A: issue all 8 window loads (8 edges per instruction, 128B contiguous/edge) ----
    const int base = wv * 64;
    uint4 vv[8];
    float rs[8];
    #pragma unroll
    for (int t = 0; t < 8; ++t) {
        int off = m_off[base + t * 8 + grp];
        rs[t]   = m_res[base + t * 8 + grp];
        const unsigned short* wb = temb + (size_t)(unsigned)off + row * H_NUM;
        vv[t] = *(const uint4*)wb;           // 16B/lane, 8 lanes contiguous per edge
    }

    // ---- phase B: rbf weight, 8-head partials, reduce-scatter over rows ----
    const float rowsp = (float)row * SPACING;
    const bool b0 = (row & 1) != 0;
    const bool b1 = (row & 2) != 0;
    const bool b2 = (row & 4) != 0;
    float* ob = out + (size_t)we0 * H_NUM + lane;   // store addr: we0*8 + t*64 + lane

    #pragma unroll
    for (int t = 0; t < 8; ++t) {
        float diff = rs[t] - rowsp;
        float rb = __expf(RBF_COEFF * diff * diff);
        uint4 v = vv[t];
        float a0 = rb * bf_lo(v.x), a1 = rb * bf_hi(v.x);
        float a2 = rb * bf_lo(v.y), a3 = rb * bf_hi(v.y);
        float a4 = rb * bf_lo(v.z), a5 = rb * bf_hi(v.z);
        float a6 = rb * bf_lo(v.w), a7 = rb * bf_hi(v.w);

        // round 1 (xor 1): keep heads with h&1 == row&1
        float k0 = (b0 ? a1 : a0) + SWZ(b0 ? a0 : a1, SWZ_X1);
        float k1 = (b0 ? a3 : a2) + SWZ(b0 ? a2 : a3, SWZ_X1);
        float k2 = (b0 ? a5 : a4) + SWZ(b0 ? a4 : a5, SWZ_X1);
        float k3 = (b0 ? a7 : a6) + SWZ(b0 ? a6 : a7, SWZ_X1);
        // round 2 (xor 2): keep heads with h&2 == row&2
        float c0 = (b1 ? k1 : k0) + SWZ(b1 ? k0 : k1, SWZ_X2);
        float c1 = (b1 ? k3 : k2) + SWZ(b1 ? k2 : k3, SWZ_X2);
        // round 3 (xor 4): lane `row` ends with head `row`, summed over all 8 rows
        float r8 = (b2 ? c1 : c0) + SWZ(b2 ? c0 : c1, SWZ_X4);

        if (we0 + t * 8 + grp < n_edges)
            __builtin_nontemporal_store(r8, ob + t * 64);   // coalesced 256B/instr
    }
}

// ---------------- Fallback (ws-free): exact fp32 direct kernel ----------------
__global__ __launch_bounds__(BLOCK_THREADS) void direct_kernel(
    const int* __restrict__ anum,
    const int* __restrict__ edge_index,
    const float* __restrict__ dist,
    const float* __restrict__ emb,
    float* __restrict__ out,
    int n_edges)
{
    __shared__ int   pair_s[32];
    __shared__ float dist_sd[32];
    __shared__ float rbf_sd[32 * G_NUM];

    const int tid = threadIdx.x;
    const int e0  = blockIdx.x * 32;

    if (tid < 32) {
        int e = e0 + tid;
        if (e >= n_edges) e = n_edges - 1;
        int s  = edge_index[e];
        int d  = edge_index[n_edges + e];
        pair_s[tid] = (anum[s] * NE_NUM + anum[d]) * (H_NUM * G_NUM);
        dist_sd[tid] = dist[e];
    }
    __syncthreads();

    for (int idx = tid; idx < 32 * G_NUM; idx += BLOCK_THREADS) {
        int el = idx / G_NUM;
        int g  = idx - el * G_NUM;
        float diff = dist_sd[el] - (float)g * SPACING;
        rbf_sd[idx] = __expf(RBF_COEFF * diff * diff);
    }
    __syncthreads();

    const int el = tid >> 3;
    const int h  = tid & 7;
    const float* ebase = emb + pair_s[el] + h * G_NUM;
    const float* rbase = rbf_sd + el * G_NUM;

    float acc = 0.0f;
    #pragma unroll
    for (int g2 = 0; g2 < G_NUM / 2; ++g2) {
        float2 ev = *(const float2*)(ebase + 2 * g2);
        float2 rv = *(const float2*)(rbase + 2 * g2);
        acc += ev.x * rv.x + ev.y * rv.y;
    }

    if (e0 + el < n_edges)
        out[e0 * H_NUM + tid] = acc;
}

extern "C" void kernel_launch(void* const* d_in, const int* in_sizes, int n_in,
                              void* d_out, int out_size, void* d_ws, size_t ws_size,
                              hipStream_t stream) {
    const int*   anum       = (const int*)d_in[0];
    const int*   edge_index = (const int*)d_in[1];
    const float* dist       = (const float*)d_in[2];
    const float* emb        = (const float*)d_in[3];
    float*       out        = (float*)d_out;
    const int n_edges = in_sizes[2];

    const size_t temb_bytes = (size_t)N_PAIRS * H_NUM * G_NUM * sizeof(unsigned short); // 8 MB

    if (ws_size < temb_bytes) {
        const int grid = (n_edges + 31) / 32;
        direct_kernel<<<grid, BLOCK_THREADS, 0, stream>>>(
            anum, edge_index, dist, emb, out, n_edges);
        return;
    }

    unsigned int* temb = (unsigned int*)d_ws;

    transpose_cast_kernel<<<N_PAIRS / TP_PAIRS, BLOCK_THREADS, 0, stream>>>(emb, temb);

    const int grid = (n_edges + BLOCK_THREADS - 1) / BLOCK_THREADS;
    gather_kernel<<<grid, BLOCK_THREADS, 0, stream>>>(
        anum, edge_index, dist, (const unsigned short*)temb, out, n_edges);
}